// Round 1
// baseline (582.380 us; speedup 1.0000x reference)
//
#include <hip/hip_runtime.h>
#include <hip/hip_bf16.h>

// Problem constants (fixed by setup_inputs)
#define E_    8
#define DIN   2048
#define DOUT  2048
#define N_TOK 4096
#define NK    8192
#define R_    16

typedef __bf16 bf16x8 __attribute__((ext_vector_type(8)));
typedef float  f32x4  __attribute__((ext_vector_type(4)));

static __device__ __forceinline__ void gld16(const void* g, void* l) {
  __builtin_amdgcn_global_load_lds(
      (const __attribute__((address_space(1))) unsigned int*)g,
      (__attribute__((address_space(3))) unsigned int*)l, 16, 0, 0);
}

static __device__ __forceinline__ float bfu2f(unsigned short u) {
  union { unsigned int u; float f; } v; v.u = ((unsigned int)u) << 16; return v.f;
}
static __device__ __forceinline__ unsigned short f2bfu(float f) {
  union { float f; unsigned int u; } v; v.f = f;
  unsigned int r = v.u + 0x7fffu + ((v.u >> 16) & 1u);  // round-to-nearest-even
  return (unsigned short)(r >> 16);
}

// ---- weight fp32 -> bf16 ----
__global__ void k_conv_w(const float* __restrict__ w, unsigned short* __restrict__ wb) {
  const long long n4 = (long long)E_ * DOUT * DIN / 4;
  long long i = (long long)blockIdx.x * blockDim.x + threadIdx.x;
  const long long stride = (long long)gridDim.x * blockDim.x;
  for (; i < n4; i += stride) {
    float4 v = ((const float4*)w)[i];
    ushort4 o;
    o.x = f2bfu(v.x); o.y = f2bfu(v.y); o.z = f2bfu(v.z); o.w = f2bfu(v.w);
    ((ushort4*)wb)[i] = o;
  }
}

// ---- gather token rows into sorted order (bf16), plus gate & token per slot ----
__global__ void k_gather(const float* __restrict__ x, const int* __restrict__ ssi,
                         const float* __restrict__ gates, const int* __restrict__ kptr,
                         unsigned short* __restrict__ Xs, float* __restrict__ gate,
                         int* __restrict__ tok) {
  int s = blockIdx.x;
  int ssv = ssi[s];
  int kk = kptr[0];
  int t = ssv / kk, sl = ssv - t * kk;
  if (threadIdx.x == 0) { gate[s] = gates[t * kk + sl]; tok[s] = t; }
  const float4* src = (const float4*)(x + (long long)t * DIN);
  ushort4* dst = (ushort4*)(Xs + (long long)s * DIN);
  for (int i = threadIdx.x; i < DIN / 4; i += blockDim.x) {
    float4 v = src[i];
    ushort4 o;
    o.x = f2bfu(v.x); o.y = f2bfu(v.y); o.z = f2bfu(v.z); o.w = f2bfu(v.w);
    dst[i] = o;
  }
}

// ---- XA[s][r] = 2 * dot(Xs[s,:], lora_A[e(s)][r,:])   (SCALING=2 folded in) ----
__global__ void k_xa(const unsigned short* __restrict__ Xs, const float* __restrict__ A,
                     const int* __restrict__ sei, float* __restrict__ XA) {
  int r = threadIdx.x & 15;
  int g = threadIdx.x >> 4;  // 0..15
  for (int p = 0; p < 2; p++) {
    int s = blockIdx.x * 32 + g + 16 * p;
    int e = sei[s];
    const ushort4* xr = (const ushort4*)(Xs + (long long)s * DIN);
    const float4*  ar = (const float4*)(A + ((long long)e * R_ + r) * DIN);
    float acc = 0.f;
    for (int i = 0; i < DIN / 4; i++) {
      ushort4 xv = xr[i]; float4 av = ar[i];
      acc += bfu2f(xv.x) * av.x + bfu2f(xv.y) * av.y +
             bfu2f(xv.z) * av.z + bfu2f(xv.w) * av.w;
    }
    XA[(long long)s * R_ + r] = 2.0f * acc;
  }
}

// ---- grouped GEMM (B^T form) + LoRA epilogue + gated atomic scatter ----
__global__ void __launch_bounds__(256)
k_gemm(const unsigned short* __restrict__ Xs, const unsigned short* __restrict__ Wb,
       const float* __restrict__ XA, const float* __restrict__ loraB,
       const float* __restrict__ gate, const int* __restrict__ tok,
       const int* __restrict__ eoff, float* __restrict__ out) {
  __shared__ alignas(16) unsigned short sAB[2 * 128 * 64];  // A tile | B tile, 32 KB

  // tile assignment: scan expert offsets, grid.x covers sum(ceil(Me/128)) <= 72
  int tile = blockIdx.x;
  int off_prev = 0, e = -1, m_start = 0, m_end = 0, acc_t = 0;
#pragma unroll
  for (int i = 0; i < E_; i++) {
    int oe = eoff[i];
    int Me = oe - off_prev;
    int te = (Me + 127) >> 7;
    if (e < 0 && tile < acc_t + te) {
      e = i; m_start = off_prev + (tile - acc_t) * 128; m_end = oe;
    }
    acc_t += te;
    off_prev = oe;
  }
  if (e < 0) return;
  const int n_start = blockIdx.y * 128;

  const int tid = threadIdx.x;
  const int w = tid >> 6, lane = tid & 63;
  const int wm = w & 1, wn = w >> 1;
  const int quad = lane >> 4, l15 = lane & 15;

  f32x4 acc[4][4];
#pragma unroll
  for (int mi = 0; mi < 4; mi++)
#pragma unroll
    for (int ni = 0; ni < 4; ni++)
      acc[mi][ni] = (f32x4){0.f, 0.f, 0.f, 0.f};

  const int srow = lane >> 3;        // row within 8-row staging chunk
  const int scol = (lane & 7) * 8;   // bf16 col offset within BK=64
  const unsigned short* Wbase = Wb + (long long)e * DOUT * DIN;

  for (int kt = 0; kt < DIN / 64; kt++) {
    const int k0 = kt * 64;
#pragma unroll
    for (int j = 0; j < 4; j++) {
      int c = w * 4 + j;              // chunk 0..15 (8 rows x 64 cols each)
      int rt = c * 8 + srow;
      int ga = m_start + rt; if (ga >= m_end) ga = m_end - 1;  // clamp partial tile
      gld16(Xs + (long long)ga * DIN + k0 + scol, &sAB[c * 512 + lane * 8]);
      gld16(Wbase + (long long)(n_start + rt) * DIN + k0 + scol,
            &sAB[8192 + c * 512 + lane * 8]);
    }
    __syncthreads();
#pragma unroll
    for (int ks = 0; ks < 2; ks++) {
      const int ko = ks * 32 + quad * 8;
      bf16x8 af[4], bfr[4];
#pragma unroll
      for (int mi = 0; mi < 4; mi++)
        af[mi] = *(const bf16x8*)&sAB[(wm * 64 + mi * 16 + l15) * 64 + ko];
#pragma unroll
      for (int ni = 0; ni < 4; ni++)
        bfr[ni] = *(const bf16x8*)&sAB[8192 + (wn * 64 + ni * 16 + l15) * 64 + ko];
#pragma unroll
      for (int mi = 0; mi < 4; mi++)
#pragma unroll
        for (int ni = 0; ni < 4; ni++)
          acc[mi][ni] = __builtin_amdgcn_mfma_f32_16x16x32_bf16(
              af[mi], bfr[ni], acc[mi][ni], 0, 0, 0);
    }
    __syncthreads();
  }

  // ---- epilogue: stage XA tile, loraB tile (pad 17), gates, tokens in LDS ----
  float* XAs = (float*)(sAB);            // 128*16 f32  @ byte 0
  float* Bls = (float*)(sAB + 4096);     // 128*17 f32  @ byte 8192 (padded stride)
  float* gs  = (float*)(sAB + 8448);     // 128 f32     @ byte 16896
  int*   ts  = (int*)(sAB + 8704);       // 128 i32     @ byte 17408

  for (int idx = tid; idx < 512; idx += 256) {   // XA: 512 float4
    int row = idx >> 2, part = idx & 3;
    int gm = m_start + row; if (gm >= m_end) gm = m_end - 1;
    ((float4*)XAs)[idx] = ((const float4*)(XA + (long long)gm * 16))[part];
  }
  for (int idx = tid; idx < 2048; idx += 256) {  // loraB, scalar into padded rows
    int row = idx >> 4, r = idx & 15;
    Bls[row * 17 + r] = loraB[((long long)e * DOUT + n_start + row) * 16 + r];
  }
  if (tid < 128) {
    int gm = m_start + tid; if (gm >= m_end) gm = m_end - 1;
    gs[tid] = gate[gm];
    ts[tid] = tok[gm];
  }
  __syncthreads();

#pragma unroll
  for (int ni = 0; ni < 4; ni++) {
    int col = wn * 64 + ni * 16 + l15;
    float bv[16];
#pragma unroll
    for (int r = 0; r < 16; r++) bv[r] = Bls[col * 17 + r];
    int n = n_start + col;
#pragma unroll
    for (int mi = 0; mi < 4; mi++) {
#pragma unroll
      for (int t4 = 0; t4 < 4; t4++) {
        int row = wm * 64 + mi * 16 + quad * 4 + t4;
        if (m_start + row >= m_end) continue;    // partial tile guard
        float lv = 0.f;
#pragma unroll
        for (int r = 0; r < 16; r++) lv += XAs[row * 16 + r] * bv[r];
        float o = (acc[mi][ni][t4] + lv) * gs[row];
        atomicAdd(out + (long long)ts[row] * DOUT + n, o);  // exactly k=2 adds/elem -> deterministic
      }
    }
  }
}

extern "C" void kernel_launch(void* const* d_in, const int* in_sizes, int n_in,
                              void* d_out, int out_size, void* d_ws, size_t ws_size,
                              hipStream_t stream) {
  (void)in_sizes; (void)n_in; (void)out_size; (void)ws_size;
  const float* inputs = (const float*)d_in[0];
  const float* weight = (const float*)d_in[1];
  const float* lora_A = (const float*)d_in[2];
  const float* lora_B = (const float*)d_in[3];
  const float* gates  = (const float*)d_in[4];
  const int* sei  = (const int*)d_in[5];
  const int* ssi  = (const int*)d_in[6];
  const int* eoff = (const int*)d_in[7];
  const int* kptr = (const int*)d_in[8];
  float* out = (float*)d_out;

  // workspace layout (needs ~101.3 MB)
  unsigned char* ws = (unsigned char*)d_ws;
  unsigned short* Wb = (unsigned short*)ws;                // 8*2048*2048*2   = 67,108,864 B
  unsigned short* Xs = (unsigned short*)(ws + 67108864);   // 8192*2048*2     = 33,554,432 B
  float* XA   = (float*)(ws + 100663296);                  // 8192*16*4       =    524,288 B
  float* gate = (float*)(ws + 101187584);                  // 8192*4
  int*   tok  = (int*)(ws + 101220352);                    // 8192*4

  hipMemsetAsync(d_out, 0, (size_t)N_TOK * DOUT * sizeof(float), stream);
  k_conv_w<<<8192, 256, 0, stream>>>(weight, Wb);
  k_gather<<<NK, 256, 0, stream>>>(inputs, ssi, gates, kptr, Xs, gate, tok);
  k_xa<<<256, 256, 0, stream>>>(Xs, lora_A, sei, XA);
  dim3 g(72, 16);
  k_gemm<<<g, 256, 0, stream>>>(Xs, Wb, XA, lora_B, gate, tok, eoff, out);
}

// Round 2
// 493.037 us; speedup vs baseline: 1.1812x; 1.1812x over previous
//
#include <hip/hip_runtime.h>
#include <hip/hip_bf16.h>

// Problem constants (fixed by setup_inputs)
#define E_    8
#define DIN   2048
#define DOUT  2048
#define N_TOK 4096
#define NK    8192
#define R_    16

typedef __bf16 bf16x8 __attribute__((ext_vector_type(8)));
typedef float  f32x4  __attribute__((ext_vector_type(4)));
typedef unsigned short u16x8 __attribute__((ext_vector_type(8)));

static __device__ __forceinline__ void gld16(const void* g, void* l) {
  __builtin_amdgcn_global_load_lds(
      (const __attribute__((address_space(1))) unsigned int*)g,
      (__attribute__((address_space(3))) unsigned int*)l, 16, 0, 0);
}

static __device__ __forceinline__ float bfu2f(unsigned short u) {
  union { unsigned int u; float f; } v; v.u = ((unsigned int)u) << 16; return v.f;
}
static __device__ __forceinline__ unsigned short f2bfu(float f) {
  union { float f; unsigned int u; } v; v.f = f;
  unsigned int r = v.u + 0x7fffu + ((v.u >> 16) & 1u);  // round-to-nearest-even
  return (unsigned short)(r >> 16);
}

// ---- fp32 -> bf16 streaming convert (used for weight and lora_A) ----
__global__ void k_conv(const float* __restrict__ w, unsigned short* __restrict__ wb,
                       long long n4) {
  long long i = (long long)blockIdx.x * blockDim.x + threadIdx.x;
  const long long stride = (long long)gridDim.x * blockDim.x;
  for (; i < n4; i += stride) {
    float4 v = ((const float4*)w)[i];
    ushort4 o;
    o.x = f2bfu(v.x); o.y = f2bfu(v.y); o.z = f2bfu(v.z); o.w = f2bfu(v.w);
    ((ushort4*)wb)[i] = o;
  }
}

// ---- gather token rows into sorted order (bf16), plus gate & token per slot ----
__global__ void k_gather(const float* __restrict__ x, const int* __restrict__ ssi,
                         const float* __restrict__ gates, const int* __restrict__ kptr,
                         unsigned short* __restrict__ Xs, float* __restrict__ gate,
                         int* __restrict__ tok) {
  int s = blockIdx.x;
  int ssv = ssi[s];
  int kk = kptr[0];
  int t = ssv / kk, sl = ssv - t * kk;
  if (threadIdx.x == 0) { gate[s] = gates[t * kk + sl]; tok[s] = t; }
  const float4* src = (const float4*)(x + (long long)t * DIN);
  ushort4* dst = (ushort4*)(Xs + (long long)s * DIN);
  for (int i = threadIdx.x; i < DIN / 4; i += blockDim.x) {
    float4 v = src[i];
    ushort4 o;
    o.x = f2bfu(v.x); o.y = f2bfu(v.y); o.z = f2bfu(v.z); o.w = f2bfu(v.w);
    dst[i] = o;
  }
}

// ---- XA[s][r] = 2 * dot(Xs[s,:], lora_A_bf16[e(s)][r,:]) ; one wave per slot ----
__global__ void __launch_bounds__(64)
k_xa(const unsigned short* __restrict__ Xs, const unsigned short* __restrict__ Ab,
     const int* __restrict__ sei, float* __restrict__ XA) {
  __shared__ alignas(16) unsigned short xrow[DIN];
  const int s = blockIdx.x;
  const int tid = threadIdx.x;
  const int e = sei[s];
  // stage x row: 2048 shorts = 256 x u16x8; 64 lanes x 4 iters, coalesced
  const u16x8* src = (const u16x8*)(Xs + (long long)s * DIN);
#pragma unroll
  for (int i = 0; i < 4; i++)
    *(u16x8*)&xrow[(tid + i * 64) * 8] = src[tid + i * 64];
  __syncthreads();

  const int r = tid & 15, seg = tid >> 4;      // 16 r x 4 segments of 512
  const unsigned short* arow = Ab + ((long long)e * R_ + r) * DIN + seg * 512;
  const unsigned short* xseg = xrow + seg * 512;
  float acc = 0.f;
#pragma unroll 8
  for (int j = 0; j < 64; j++) {
    u16x8 xv = *(const u16x8*)(xseg + j * 8);   // broadcast across the 16 r-lanes
    u16x8 av = *(const u16x8*)(arow + j * 8);
#pragma unroll
    for (int t = 0; t < 8; t++) acc += bfu2f(xv[t]) * bfu2f(av[t]);
  }
  acc += __shfl_xor(acc, 16);
  acc += __shfl_xor(acc, 32);
  if (tid < 16) XA[(long long)s * R_ + r] = 2.0f * acc;
}

// ---- grouped GEMM (B^T form) + LoRA epilogue + gated atomic scatter ----
// LDS layout is XOR-swizzled: element (row, colchunk cc) lives at slot cc^(row&7);
// gld16 forces dest = base + lane*16, so the swizzle is applied on the SOURCE col.
__global__ void __launch_bounds__(256)
k_gemm(const unsigned short* __restrict__ Xs, const unsigned short* __restrict__ Wb,
       const float* __restrict__ XA, const float* __restrict__ loraB,
       const float* __restrict__ gate, const int* __restrict__ tok,
       const int* __restrict__ eoff, float* __restrict__ out) {
  __shared__ alignas(16) unsigned short sAB[2 * 128 * 64];  // A tile | B tile, 32 KB

  // tile assignment: scan expert offsets, grid.x covers sum(ceil(Me/128)) <= 72
  int tile = blockIdx.x;
  int off_prev = 0, e = -1, m_start = 0, m_end = 0, acc_t = 0;
#pragma unroll
  for (int i = 0; i < E_; i++) {
    int oe = eoff[i];
    int Me = oe - off_prev;
    int te = (Me + 127) >> 7;
    if (e < 0 && tile < acc_t + te) {
      e = i; m_start = off_prev + (tile - acc_t) * 128; m_end = oe;
    }
    acc_t += te;
    off_prev = oe;
  }
  if (e < 0) return;
  const int n_start = blockIdx.y * 128;

  const int tid = threadIdx.x;
  const int w = tid >> 6, lane = tid & 63;
  const int wm = w & 1, wn = w >> 1;
  const int quad = lane >> 4, l15 = lane & 15;

  f32x4 acc[4][4];
#pragma unroll
  for (int mi = 0; mi < 4; mi++)
#pragma unroll
    for (int ni = 0; ni < 4; ni++)
      acc[mi][ni] = (f32x4){0.f, 0.f, 0.f, 0.f};

  const int srow = lane >> 3;              // row within 8-row staging chunk
  const int scol = ((lane & 7) ^ srow) * 8;  // SWIZZLED source bf16 col within BK=64
  const unsigned short* Wbase = Wb + (long long)e * DOUT * DIN;

  for (int kt = 0; kt < DIN / 64; kt++) {
    const int k0 = kt * 64;
#pragma unroll
    for (int j = 0; j < 4; j++) {
      int c = w * 4 + j;              // chunk 0..15 (8 rows x 64 cols each)
      int rt = c * 8 + srow;
      int ga = m_start + rt; if (ga >= m_end) ga = m_end - 1;  // clamp partial tile
      gld16(Xs + (long long)ga * DIN + k0 + scol, &sAB[c * 512 + lane * 8]);
      gld16(Wbase + (long long)(n_start + rt) * DIN + k0 + scol,
            &sAB[8192 + c * 512 + lane * 8]);
    }
    __syncthreads();
#pragma unroll
    for (int ks = 0; ks < 2; ks++) {
      // swizzled read: colchunk kc = ks*4+quad lives at slot kc^(row&7); row&7 == l15&7
      const int kx = (((ks << 2) | quad) ^ (l15 & 7)) << 3;
      bf16x8 af[4], bfr[4];
#pragma unroll
      for (int mi = 0; mi < 4; mi++)
        af[mi] = *(const bf16x8*)&sAB[(wm * 64 + mi * 16 + l15) * 64 + kx];
#pragma unroll
      for (int ni = 0; ni < 4; ni++)
        bfr[ni] = *(const bf16x8*)&sAB[8192 + (wn * 64 + ni * 16 + l15) * 64 + kx];
#pragma unroll
      for (int mi = 0; mi < 4; mi++)
#pragma unroll
        for (int ni = 0; ni < 4; ni++)
          acc[mi][ni] = __builtin_amdgcn_mfma_f32_16x16x32_bf16(
              af[mi], bfr[ni], acc[mi][ni], 0, 0, 0);
    }
    __syncthreads();
  }

  // ---- epilogue: stage XA tile, loraB tile (pad 17), gates, tokens in LDS ----
  float* XAs = (float*)(sAB);            // 128*16 f32  @ byte 0
  float* Bls = (float*)(sAB + 4096);     // 128*17 f32  @ byte 8192 (padded stride)
  float* gs  = (float*)(sAB + 8448);     // 128 f32     @ byte 16896
  int*   ts  = (int*)(sAB + 8704);       // 128 i32     @ byte 17408

  for (int idx = tid; idx < 512; idx += 256) {   // XA: 512 float4
    int row = idx >> 2, part = idx & 3;
    int gm = m_start + row; if (gm >= m_end) gm = m_end - 1;
    ((float4*)XAs)[idx] = ((const float4*)(XA + (long long)gm * 16))[part];
  }
  for (int idx = tid; idx < 2048; idx += 256) {  // loraB, scalar into padded rows
    int row = idx >> 4, r = idx & 15;
    Bls[row * 17 + r] = loraB[((long long)e * DOUT + n_start + row) * 16 + r];
  }
  if (tid < 128) {
    int gm = m_start + tid; if (gm >= m_end) gm = m_end - 1;
    gs[tid] = gate[gm];
    ts[tid] = tok[gm];
  }
  __syncthreads();

#pragma unroll
  for (int ni = 0; ni < 4; ni++) {
    int col = wn * 64 + ni * 16 + l15;
    float bv[16];
#pragma unroll
    for (int r = 0; r < 16; r++) bv[r] = Bls[col * 17 + r];
    int n = n_start + col;
#pragma unroll
    for (int mi = 0; mi < 4; mi++) {
#pragma unroll
      for (int t4 = 0; t4 < 4; t4++) {
        int row = wm * 64 + mi * 16 + quad * 4 + t4;
        if (m_start + row >= m_end) continue;    // partial tile guard
        float lv = 0.f;
#pragma unroll
        for (int r = 0; r < 16; r++) lv += XAs[row * 16 + r] * bv[r];
        float o = (acc[mi][ni][t4] + lv) * gs[row];
        atomicAdd(out + (long long)ts[row] * DOUT + n, o);  // exactly k=2 adds/elem -> deterministic
      }
    }
  }
}

extern "C" void kernel_launch(void* const* d_in, const int* in_sizes, int n_in,
                              void* d_out, int out_size, void* d_ws, size_t ws_size,
                              hipStream_t stream) {
  (void)in_sizes; (void)n_in; (void)out_size; (void)ws_size;
  const float* inputs = (const float*)d_in[0];
  const float* weight = (const float*)d_in[1];
  const float* lora_A = (const float*)d_in[2];
  const float* lora_B = (const float*)d_in[3];
  const float* gates  = (const float*)d_in[4];
  const int* sei  = (const int*)d_in[5];
  const int* ssi  = (const int*)d_in[6];
  const int* eoff = (const int*)d_in[7];
  const int* kptr = (const int*)d_in[8];
  float* out = (float*)d_out;

  // workspace layout (~101.8 MB)
  unsigned char* ws = (unsigned char*)d_ws;
  unsigned short* Wb = (unsigned short*)ws;                // 8*2048*2048*2   = 67,108,864 B
  unsigned short* Xs = (unsigned short*)(ws + 67108864);   // 8192*2048*2     = 33,554,432 B
  float* XA   = (float*)(ws + 100663296);                  // 8192*16*4       =    524,288 B
  float* gate = (float*)(ws + 101187584);                  // 8192*4
  int*   tok  = (int*)(ws + 101220352);                    // 8192*4
  unsigned short* Ab = (unsigned short*)(ws + 101253120);  // 8*16*2048*2     =    524,288 B

  hipMemsetAsync(d_out, 0, (size_t)N_TOK * DOUT * sizeof(float), stream);
  k_conv<<<8192, 256, 0, stream>>>(weight, Wb, (long long)E_ * DOUT * DIN / 4);
  k_conv<<<256, 256, 0, stream>>>(lora_A, Ab, (long long)E_ * R_ * DIN / 4);
  k_gather<<<NK, 256, 0, stream>>>(inputs, ssi, gates, kptr, Xs, gate, tok);
  k_xa<<<NK, 64, 0, stream>>>(Xs, Ab, sei, XA);
  dim3 g(72, 16);
  k_gemm<<<g, 256, 0, stream>>>(Xs, Wb, XA, lora_B, gate, tok, eoff, out);
}

// Round 3
// 446.257 us; speedup vs baseline: 1.3050x; 1.1048x over previous
//
#include <hip/hip_runtime.h>
#include <hip/hip_bf16.h>

// Problem constants (fixed by setup_inputs)
#define E_    8
#define DIN   2048
#define DOUT  2048
#define N_TOK 4096
#define NK    8192
#define R_    16
#define KEXT  2112            // 2048 + 16 (LoRA rank tail) + 48 zero pad, %64==0
#define KT_N  (KEXT / 64)     // 33 K-tiles

typedef __bf16 bf16x8 __attribute__((ext_vector_type(8)));
typedef float  f32x4  __attribute__((ext_vector_type(4)));
typedef unsigned short u16x8 __attribute__((ext_vector_type(8)));

static __device__ __forceinline__ void gld16(const void* g, void* l) {
  __builtin_amdgcn_global_load_lds(
      (const __attribute__((address_space(1))) unsigned int*)g,
      (__attribute__((address_space(3))) unsigned int*)l, 16, 0, 0);
}

static __device__ __forceinline__ float bfu2f(unsigned short u) {
  union { unsigned int u; float f; } v; v.u = ((unsigned int)u) << 16; return v.f;
}
static __device__ __forceinline__ unsigned short f2bfu(float f) {
  union { float f; unsigned int u; } v; v.f = f;
  unsigned int r = v.u + 0x7fffu + ((v.u >> 16) & 1u);  // round-to-nearest-even
  return (unsigned short)(r >> 16);
}

// ---- build Wbe[e][n][KEXT]: bf16(W) | bf16(loraB) | zeros. One 64-thr block per row ----
__global__ void __launch_bounds__(64)
k_wconv(const float* __restrict__ w, const float* __restrict__ lb,
        unsigned short* __restrict__ wbe) {
  const long long row = blockIdx.x;                 // e*DOUT + n, 0..16383
  const float4* src  = (const float4*)(w + row * DIN);
  const float4* lsrc = (const float4*)(lb + row * R_);
  ushort4* dst = (ushort4*)(wbe + row * KEXT);
  for (int u = threadIdx.x; u < KEXT / 4; u += 64) {
    float4 v;
    if (u < 512)       v = src[u];
    else if (u < 516)  v = lsrc[u - 512];
    else               v = make_float4(0.f, 0.f, 0.f, 0.f);
    ushort4 o;
    o.x = f2bfu(v.x); o.y = f2bfu(v.y); o.z = f2bfu(v.z); o.w = f2bfu(v.w);
    dst[u] = o;
  }
}

// ---- lora_A fp32 -> bf16 ----
__global__ void k_aconv(const float* __restrict__ a, unsigned short* __restrict__ ab) {
  long long i = (long long)blockIdx.x * blockDim.x + threadIdx.x;   // n4 = 65536
  float4 v = ((const float4*)a)[i];
  ushort4 o;
  o.x = f2bfu(v.x); o.y = f2bfu(v.y); o.z = f2bfu(v.z); o.w = f2bfu(v.w);
  ((ushort4*)ab)[i] = o;
}

// ---- gather token rows into Xe (bf16, stride KEXT), zero the pad tail ----
__global__ void k_gather(const float* __restrict__ x, const int* __restrict__ ssi,
                         const float* __restrict__ gates, const int* __restrict__ kptr,
                         unsigned short* __restrict__ Xe, float* __restrict__ gate,
                         int* __restrict__ tok) {
  int s = blockIdx.x;
  int ssv = ssi[s];
  int kk = kptr[0];
  int t = ssv / kk, sl = ssv - t * kk;
  if (threadIdx.x == 0) { gate[s] = gates[t * kk + sl]; tok[s] = t; }
  const float4* src = (const float4*)(x + (long long)t * DIN);
  ushort4* dst = (ushort4*)(Xe + (long long)s * KEXT);
  for (int i = threadIdx.x; i < 512; i += 256) {
    float4 v = src[i];
    ushort4 o;
    o.x = f2bfu(v.x); o.y = f2bfu(v.y); o.z = f2bfu(v.z); o.w = f2bfu(v.w);
    dst[i] = o;
  }
  if (threadIdx.x < 12) {   // zero cols 2064..2111 (XA slot 2048..2063 filled by k_xa)
    ushort4 z; z.x = z.y = z.z = z.w = 0;
    dst[516 + threadIdx.x] = z;
  }
}

// ---- XA tail: Xe[s][2048+r] = bf16( 2 * dot(x_s, lora_A[e][r]) ); one wave/slot ----
// x row staged in REGISTERS (32 f32/lane); A reads fully coalesced (u16x8 per lane).
__global__ void __launch_bounds__(64)
k_xa(unsigned short* __restrict__ Xe, const unsigned short* __restrict__ Ab,
     const int* __restrict__ sei) {
  const int s = blockIdx.x;
  const int tid = threadIdx.x;
  const int e = sei[s];
  const u16x8* xr = (const u16x8*)(Xe + (long long)s * KEXT);
  float xf[32];
#pragma unroll
  for (int i = 0; i < 4; i++) {
    u16x8 xv = xr[tid + i * 64];
#pragma unroll
    for (int t = 0; t < 8; t++) xf[i * 8 + t] = bfu2f(xv[t]);
  }
#pragma unroll
  for (int r = 0; r < 16; r++) {
    const u16x8* ar = (const u16x8*)(Ab + ((long long)e * R_ + r) * DIN);
    float acc = 0.f;
#pragma unroll
    for (int i = 0; i < 4; i++) {
      u16x8 av = ar[tid + i * 64];
#pragma unroll
      for (int t = 0; t < 8; t++) acc += xf[i * 8 + t] * bfu2f(av[t]);
    }
    acc += __shfl_xor(acc, 1);  acc += __shfl_xor(acc, 2);
    acc += __shfl_xor(acc, 4);  acc += __shfl_xor(acc, 8);
    acc += __shfl_xor(acc, 16); acc += __shfl_xor(acc, 32);
    if (tid == 0) Xe[(long long)s * KEXT + 2048 + r] = f2bfu(2.0f * acc);
  }
}

// ---- grouped GEMM over extended K (LoRA folded) + gated atomic scatter ----
// LDS XOR-swizzle: element (row, colchunk cc) lives at slot cc^(row&7); swizzle on SOURCE col.
__global__ void __launch_bounds__(256)
k_gemm(const unsigned short* __restrict__ Xe, const unsigned short* __restrict__ Wbe,
       const float* __restrict__ gate, const int* __restrict__ tok,
       const int* __restrict__ eoff, float* __restrict__ out) {
  __shared__ alignas(16) unsigned short sAB[2 * 128 * 64];  // A tile | B tile, 32 KB
  __shared__ float gs[128];
  __shared__ int   ts[128];

  // tile assignment: scan expert offsets; grid.x covers sum(ceil(Me/128)) <= 72
  int tile = blockIdx.x;
  int off_prev = 0, e = -1, m_start = 0, m_end = 0, acc_t = 0;
#pragma unroll
  for (int i = 0; i < E_; i++) {
    int oe = eoff[i];
    int Me = oe - off_prev;
    int te = (Me + 127) >> 7;
    if (e < 0 && tile < acc_t + te) {
      e = i; m_start = off_prev + (tile - acc_t) * 128; m_end = oe;
    }
    acc_t += te;
    off_prev = oe;
  }
  if (e < 0) return;
  const int n_start = blockIdx.y * 128;

  const int tid = threadIdx.x;
  const int w = tid >> 6, lane = tid & 63;
  const int wm = w & 1, wn = w >> 1;
  const int quad = lane >> 4, l15 = lane & 15;

  if (tid < 128) {   // stage gates/tokens; first K-loop barrier makes them visible
    int gm = m_start + tid; if (gm >= m_end) gm = m_end - 1;
    gs[tid] = gate[gm];
    ts[tid] = tok[gm];
  }

  f32x4 acc[4][4];
#pragma unroll
  for (int mi = 0; mi < 4; mi++)
#pragma unroll
    for (int ni = 0; ni < 4; ni++)
      acc[mi][ni] = (f32x4){0.f, 0.f, 0.f, 0.f};

  const int srow = lane >> 3;                // row within 8-row staging chunk
  const int scol = ((lane & 7) ^ srow) * 8;  // SWIZZLED source bf16 col within BK=64
  const unsigned short* Wbase = Wbe + (long long)e * DOUT * KEXT;

  for (int kt = 0; kt < KT_N; kt++) {
    const int k0 = kt * 64;
#pragma unroll
    for (int j = 0; j < 4; j++) {
      int c = w * 4 + j;              // chunk 0..15 (8 rows x 64 cols each)
      int rt = c * 8 + srow;
      int ga = m_start + rt; if (ga >= m_end) ga = m_end - 1;  // clamp partial tile
      gld16(Xe + (long long)ga * KEXT + k0 + scol, &sAB[c * 512 + lane * 8]);
      gld16(Wbase + (long long)(n_start + rt) * KEXT + k0 + scol,
            &sAB[8192 + c * 512 + lane * 8]);
    }
    __syncthreads();
#pragma unroll
    for (int ks = 0; ks < 2; ks++) {
      // swizzled read: colchunk kc = ks*4+quad lives at slot kc^(row&7); row&7 == l15&7
      const int kx = (((ks << 2) | quad) ^ (l15 & 7)) << 3;
      bf16x8 af[4], bfr[4];
#pragma unroll
      for (int mi = 0; mi < 4; mi++)
        af[mi] = *(const bf16x8*)&sAB[(wm * 64 + mi * 16 + l15) * 64 + kx];
#pragma unroll
      for (int ni = 0; ni < 4; ni++)
        bfr[ni] = *(const bf16x8*)&sAB[8192 + (wn * 64 + ni * 16 + l15) * 64 + kx];
#pragma unroll
      for (int mi = 0; mi < 4; mi++)
#pragma unroll
        for (int ni = 0; ni < 4; ni++)
          acc[mi][ni] = __builtin_amdgcn_mfma_f32_16x16x32_bf16(
              af[mi], bfr[ni], acc[mi][ni], 0, 0, 0);
    }
    __syncthreads();
  }

  // ---- epilogue: gate + atomic scatter (LoRA already in acc via K-tail) ----
#pragma unroll
  for (int ni = 0; ni < 4; ni++) {
    int n = n_start + wn * 64 + ni * 16 + l15;
#pragma unroll
    for (int mi = 0; mi < 4; mi++) {
#pragma unroll
      for (int t4 = 0; t4 < 4; t4++) {
        int row = wm * 64 + mi * 16 + quad * 4 + t4;
        if (m_start + row >= m_end) continue;    // partial tile guard
        float o = acc[mi][ni][t4] * gs[row];
        atomicAdd(out + (long long)ts[row] * DOUT + n, o);  // exactly k=2 adds/elem
      }
    }
  }
}

extern "C" void kernel_launch(void* const* d_in, const int* in_sizes, int n_in,
                              void* d_out, int out_size, void* d_ws, size_t ws_size,
                              hipStream_t stream) {
  (void)in_sizes; (void)n_in; (void)out_size; (void)ws_size;
  const float* inputs = (const float*)d_in[0];
  const float* weight = (const float*)d_in[1];
  const float* lora_A = (const float*)d_in[2];
  const float* lora_B = (const float*)d_in[3];
  const float* gates  = (const float*)d_in[4];
  const int* sei  = (const int*)d_in[5];
  const int* ssi  = (const int*)d_in[6];
  const int* eoff = (const int*)d_in[7];
  const int* kptr = (const int*)d_in[8];
  float* out = (float*)d_out;

  // workspace layout (~104.4 MB)
  unsigned char* ws = (unsigned char*)d_ws;
  unsigned short* Wbe = (unsigned short*)ws;                 // 8*2048*2112*2 = 69,206,016 B
  unsigned short* Xe  = (unsigned short*)(ws + 69206016);    // 8192*2112*2   = 34,603,008 B
  unsigned short* Ab  = (unsigned short*)(ws + 103809024);   // 8*16*2048*2   =    524,288 B
  float* gate = (float*)(ws + 104333312);                    // 8192*4
  int*   tok  = (int*)(ws + 104366080);                      // 8192*4

  hipMemsetAsync(d_out, 0, (size_t)N_TOK * DOUT * sizeof(float), stream);
  k_wconv<<<E_ * DOUT, 64, 0, stream>>>(weight, lora_B, Wbe);
  k_aconv<<<256, 256, 0, stream>>>(lora_A, Ab);
  k_gather<<<NK, 256, 0, stream>>>(inputs, ssi, gates, kptr, Xe, gate, tok);
  k_xa<<<NK, 64, 0, stream>>>(Xe, Ab, sei);
  dim3 g(72, 16);
  k_gemm<<<g, 256, 0, stream>>>(Xe, Wbe, gate, tok, eoff, out);
}

// Round 4
// 435.232 us; speedup vs baseline: 1.3381x; 1.0253x over previous
//
#include <hip/hip_runtime.h>
#include <hip/hip_bf16.h>

// Problem constants (fixed by setup_inputs)
#define E_    8
#define DIN   2048
#define DOUT  2048
#define N_TOK 4096
#define NK    8192
#define R_    16
#define KEXT  2112            // 2048 + 16 (LoRA rank tail) + 48 zero pad, %64==0
#define KT_N  (KEXT / 64)     // 33 K-tiles

typedef __bf16 bf16x8 __attribute__((ext_vector_type(8)));
typedef float  f32x4  __attribute__((ext_vector_type(4)));
typedef unsigned short u16x8 __attribute__((ext_vector_type(8)));

static __device__ __forceinline__ void gld16(const void* g, void* l) {
  __builtin_amdgcn_global_load_lds(
      (const __attribute__((address_space(1))) unsigned int*)g,
      (__attribute__((address_space(3))) unsigned int*)l, 16, 0, 0);
}

static __device__ __forceinline__ unsigned short f2bfu(float f) {
  union { float f; unsigned int u; } v; v.f = f;
  unsigned int r = v.u + 0x7fffu + ((v.u >> 16) & 1u);  // round-to-nearest-even
  return (unsigned short)(r >> 16);
}

// ---- build Wbe[e][n][KEXT]: bf16(W) | bf16(loraB) | zeros. One 64-thr block per row ----
__global__ void __launch_bounds__(64)
k_wconv(const float* __restrict__ w, const float* __restrict__ lb,
        unsigned short* __restrict__ wbe) {
  const long long row = blockIdx.x;                 // e*DOUT + n, 0..16383
  const float4* src  = (const float4*)(w + row * DIN);
  const float4* lsrc = (const float4*)(lb + row * R_);
  ushort4* dst = (ushort4*)(wbe + row * KEXT);
  for (int u = threadIdx.x; u < KEXT / 4; u += 64) {
    float4 v;
    if (u < 512)       v = src[u];
    else if (u < 516)  v = lsrc[u - 512];
    else               v = make_float4(0.f, 0.f, 0.f, 0.f);
    ushort4 o;
    o.x = f2bfu(v.x); o.y = f2bfu(v.y); o.z = f2bfu(v.z); o.w = f2bfu(v.w);
    dst[u] = o;
  }
}

// ---- lora_A fp32 -> bf16 ----
__global__ void k_aconv(const float* __restrict__ a, unsigned short* __restrict__ ab) {
  long long i = (long long)blockIdx.x * blockDim.x + threadIdx.x;   // n4 = 65536
  float4 v = ((const float4*)a)[i];
  ushort4 o;
  o.x = f2bfu(v.x); o.y = f2bfu(v.y); o.z = f2bfu(v.z); o.w = f2bfu(v.w);
  ((ushort4*)ab)[i] = o;
}

// ---- gather token rows into Xe (bf16, stride KEXT), zero the pad tail ----
__global__ void k_gather(const float* __restrict__ x, const int* __restrict__ ssi,
                         const float* __restrict__ gates, const int* __restrict__ kptr,
                         unsigned short* __restrict__ Xe, float* __restrict__ gate,
                         int* __restrict__ tok) {
  int s = blockIdx.x;
  int ssv = ssi[s];
  int kk = kptr[0];
  int t = ssv / kk, sl = ssv - t * kk;
  if (threadIdx.x == 0) { gate[s] = gates[t * kk + sl]; tok[s] = t; }
  const float4* src = (const float4*)(x + (long long)t * DIN);
  ushort4* dst = (ushort4*)(Xe + (long long)s * KEXT);
  for (int i = threadIdx.x; i < 512; i += 256) {
    float4 v = src[i];
    ushort4 o;
    o.x = f2bfu(v.x); o.y = f2bfu(v.y); o.z = f2bfu(v.z); o.w = f2bfu(v.w);
    dst[i] = o;
  }
  if (threadIdx.x < 12) {   // zero cols 2064..2111 (XA slot 2048..2063 filled by k_xa)
    ushort4 z; z.x = z.y = z.z = z.w = 0;
    dst[516 + threadIdx.x] = z;
  }
}

// ---- XA tail via MFMA: Xe[s][2048+r] = bf16( 2 * dot(x_s, lora_A[e][r]) ) ----
// One wave per 16-slot expert-aligned tile: M=16 slots, N=16 ranks, K=2048.
// A-frag: lane reads Xe[row=m_start+l15][k0+quad*8..+7]; B-frag: Ab[e][r=l15][same k].
// C/D layout: col(l15)=rank r, row(quad*4+t)=slot-in-tile (m89-verified mapping).
__global__ void __launch_bounds__(64)
k_xa(unsigned short* __restrict__ Xe, const unsigned short* __restrict__ Ab,
     const int* __restrict__ eoff) {
  int tile = blockIdx.x;
  int off_prev = 0, e = -1, m_start = 0, m_end = 0, acc_t = 0;
#pragma unroll
  for (int i = 0; i < E_; i++) {
    int oe = eoff[i];
    int te = (oe - off_prev + 15) >> 4;
    if (e < 0 && tile < acc_t + te) {
      e = i; m_start = off_prev + (tile - acc_t) * 16; m_end = oe;
    }
    acc_t += te; off_prev = oe;
  }
  if (e < 0) return;
  const int lane = threadIdx.x;
  const int l15 = lane & 15, quad = lane >> 4;
  int arow = m_start + l15; if (arow >= m_end) arow = m_end - 1;  // clamp partial tile
  const unsigned short* xp = Xe + (long long)arow * KEXT + quad * 8;
  const unsigned short* bp = Ab + ((long long)e * R_ + l15) * DIN + quad * 8;
  f32x4 acc = (f32x4){0.f, 0.f, 0.f, 0.f};
#pragma unroll 8
  for (int k0 = 0; k0 < DIN; k0 += 32) {
    bf16x8 a = *(const bf16x8*)(xp + k0);
    bf16x8 b = *(const bf16x8*)(bp + k0);
    acc = __builtin_amdgcn_mfma_f32_16x16x32_bf16(a, b, acc, 0, 0, 0);
  }
#pragma unroll
  for (int t = 0; t < 4; t++) {
    int slot = m_start + quad * 4 + t;
    if (slot < m_end)
      Xe[(long long)slot * KEXT + 2048 + l15] = f2bfu(2.0f * acc[t]);
  }
}

// ---- grouped GEMM over extended K (LoRA folded) + gated atomic scatter ----
// LDS XOR-swizzle: element (row, colchunk cc) lives at slot cc^(row&7); swizzle on SOURCE col.
// 1D grid, XCD-aware: id%8 (dispatch round-robin XCD slot) owns an n-tile PAIR;
// mt-major within, so consecutive blocks on one XCD share the same W slab in L2.
__global__ void __launch_bounds__(256)
k_gemm(const unsigned short* __restrict__ Xe, const unsigned short* __restrict__ Wbe,
       const float* __restrict__ gate, const int* __restrict__ tok,
       const int* __restrict__ eoff, float* __restrict__ out) {
  __shared__ alignas(16) unsigned short sAB[2 * 128 * 64];  // A tile | B tile, 32 KB
  __shared__ float gs[128];
  __shared__ int   ts[128];

  const int id = blockIdx.x;          // 1152 blocks
  const int xcd = id & 7, local = id >> 3;   // local 0..143
  const int mt = local % 72;
  const int nt = (xcd << 1) | (local / 72);  // 0..15
  const int n_start = nt << 7;

  // m-tile scan: mt covers sum(ceil(Me/128)) <= 71
  int off_prev = 0, e = -1, m_start = 0, m_end = 0, acc_t = 0;
#pragma unroll
  for (int i = 0; i < E_; i++) {
    int oe = eoff[i];
    int te = (oe - off_prev + 127) >> 7;
    if (e < 0 && mt < acc_t + te) {
      e = i; m_start = off_prev + (mt - acc_t) * 128; m_end = oe;
    }
    acc_t += te;
    off_prev = oe;
  }
  if (e < 0) return;

  const int tid = threadIdx.x;
  const int w = tid >> 6, lane = tid & 63;
  const int wm = w & 1, wn = w >> 1;
  const int quad = lane >> 4, l15 = lane & 15;

  if (tid < 128) {   // stage gates/tokens; first K-loop barrier makes them visible
    int gm = m_start + tid; if (gm >= m_end) gm = m_end - 1;
    gs[tid] = gate[gm];
    ts[tid] = tok[gm];
  }

  f32x4 acc[4][4];
#pragma unroll
  for (int mi = 0; mi < 4; mi++)
#pragma unroll
    for (int ni = 0; ni < 4; ni++)
      acc[mi][ni] = (f32x4){0.f, 0.f, 0.f, 0.f};

  const int srow = lane >> 3;                // row within 8-row staging chunk
  const int scol = ((lane & 7) ^ srow) * 8;  // SWIZZLED source bf16 col within BK=64
  const unsigned short* Wbase = Wbe + (long long)e * DOUT * KEXT;

  for (int kt = 0; kt < KT_N; kt++) {
    const int k0 = kt * 64;
#pragma unroll
    for (int j = 0; j < 4; j++) {
      int c = w * 4 + j;              // chunk 0..15 (8 rows x 64 cols each)
      int rt = c * 8 + srow;
      int ga = m_start + rt; if (ga >= m_end) ga = m_end - 1;  // clamp partial tile
      gld16(Xe + (long long)ga * KEXT + k0 + scol, &sAB[c * 512 + lane * 8]);
      gld16(Wbase + (long long)(n_start + rt) * KEXT + k0 + scol,
            &sAB[8192 + c * 512 + lane * 8]);
    }
    __syncthreads();
#pragma unroll
    for (int ks = 0; ks < 2; ks++) {
      // swizzled read: colchunk kc = ks*4+quad lives at slot kc^(row&7); row&7 == l15&7
      const int kx = (((ks << 2) | quad) ^ (l15 & 7)) << 3;
      bf16x8 af[4], bfr[4];
#pragma unroll
      for (int mi = 0; mi < 4; mi++)
        af[mi] = *(const bf16x8*)&sAB[(wm * 64 + mi * 16 + l15) * 64 + kx];
#pragma unroll
      for (int ni = 0; ni < 4; ni++)
        bfr[ni] = *(const bf16x8*)&sAB[8192 + (wn * 64 + ni * 16 + l15) * 64 + kx];
#pragma unroll
      for (int mi = 0; mi < 4; mi++)
#pragma unroll
        for (int ni = 0; ni < 4; ni++)
          acc[mi][ni] = __builtin_amdgcn_mfma_f32_16x16x32_bf16(
              af[mi], bfr[ni], acc[mi][ni], 0, 0, 0);
    }
    __syncthreads();
  }

  // ---- epilogue: gate + atomic scatter (LoRA already in acc via K-tail) ----
#pragma unroll
  for (int ni = 0; ni < 4; ni++) {
    int n = n_start + wn * 64 + ni * 16 + l15;
#pragma unroll
    for (int mi = 0; mi < 4; mi++) {
#pragma unroll
      for (int t4 = 0; t4 < 4; t4++) {
        int row = wm * 64 + mi * 16 + quad * 4 + t4;
        if (m_start + row >= m_end) continue;    // partial tile guard
        float o = acc[mi][ni][t4] * gs[row];
        atomicAdd(out + (long long)ts[row] * DOUT + n, o);  // exactly k=2 adds/elem
      }
    }
  }
}

extern "C" void kernel_launch(void* const* d_in, const int* in_sizes, int n_in,
                              void* d_out, int out_size, void* d_ws, size_t ws_size,
                              hipStream_t stream) {
  (void)in_sizes; (void)n_in; (void)out_size; (void)ws_size;
  const float* inputs = (const float*)d_in[0];
  const float* weight = (const float*)d_in[1];
  const float* lora_A = (const float*)d_in[2];
  const float* lora_B = (const float*)d_in[3];
  const float* gates  = (const float*)d_in[4];
  const int* sei  = (const int*)d_in[5];
  const int* ssi  = (const int*)d_in[6];
  const int* eoff = (const int*)d_in[7];
  const int* kptr = (const int*)d_in[8];
  (void)sei;
  float* out = (float*)d_out;

  // workspace layout (~104.4 MB)
  unsigned char* ws = (unsigned char*)d_ws;
  unsigned short* Wbe = (unsigned short*)ws;                 // 8*2048*2112*2 = 69,206,016 B
  unsigned short* Xe  = (unsigned short*)(ws + 69206016);    // 8192*2112*2   = 34,603,008 B
  unsigned short* Ab  = (unsigned short*)(ws + 103809024);   // 8*16*2048*2   =    524,288 B
  float* gate = (float*)(ws + 104333312);                    // 8192*4
  int*   tok  = (int*)(ws + 104366080);                      // 8192*4

  hipMemsetAsync(d_out, 0, (size_t)N_TOK * DOUT * sizeof(float), stream);
  k_wconv<<<E_ * DOUT, 64, 0, stream>>>(weight, lora_B, Wbe);
  k_aconv<<<256, 256, 0, stream>>>(lora_A, Ab);
  k_gather<<<NK, 256, 0, stream>>>(inputs, ssi, gates, kptr, Xe, gate, tok);
  k_xa<<<519, 64, 0, stream>>>(Xe, Ab, eoff);
  k_gemm<<<1152, 256, 0, stream>>>(Xe, Wbe, gate, tok, eoff, out);
}